// Round 2
// baseline (298.676 us; speedup 1.0000x reference)
//
#include <hip/hip_runtime.h>

// Postprocess: spherical->xyz + kinematic-tree prefix sum.
// obs:  (4096, 16, 96) fp32   pred: (4096, 64, 66) fp32   out: (4096, 64, 96) fp32
//
// 4 lanes per row: lanes 4g+j (j=0..3) redundantly compute row g's full
// 22-edge chain (compute is ~2% of the pipe), each lane stores float4s
// #(4i+j), i=0..5. Per store instruction the wave writes 16 FULL 64B lines
// -> no partial-line writes, no read-for-ownership (round-1 counters showed
// 1.88x write amplification + 1.5x fetch from per-thread 384B-row stores).

constexpr int NB = 4096;
constexpr int NT = 64;
constexpr int ROWS = NB * NT;        // 262144 rows (b*64+t)
constexpr int BLOCK = 256;           // 64 rows per block
constexpr int GRID = ROWS * 4 / BLOCK;

__global__ __launch_bounds__(BLOCK) void postproc_kernel(
    const float* __restrict__ obs,
    const float* __restrict__ pred,
    float* __restrict__ out)
{
    const int t   = blockIdx.x * BLOCK + threadIdx.x;
    const int row = t >> 2;          // global (b,t) row
    const int j   = t & 3;           // quarter index within the row
    const int b   = row >> 6;

    // ---- load 66 pred floats (r,theta,phi x22); 4-way broadcast in-wave ----
    float pr[66];
    {
        const float2* p2 = reinterpret_cast<const float2*>(pred + (long)row * 66);
        #pragma unroll
        for (int i = 0; i < 33; ++i) {
            const float2 v = p2[i];
            pr[2*i]   = v.x;
            pr[2*i+1] = v.y;
        }
    }

    float x[32][3];

    // ---- root joints from last observed frame (frame 15) ----
    {
        const float* ob = obs + (long)b * (16 * 96) + 15 * 96;
        constexpr int ic[4] = {0, 1, 6, 11};
        #pragma unroll
        for (int i = 0; i < 4; ++i) {
            #pragma unroll
            for (int c = 0; c < 3; ++c) x[ic[i]][c] = ob[ic[i]*3 + c];
        }
    }

    // ---- fused spherical->xyz + tree accumulation (topological order) ----
    constexpr int par[22] = {11,12,13,14,13,25,26,27,29,13,17,18,19,21, 1, 2, 3, 4, 6, 7, 8, 9};
    constexpr int chi[22] = {12,13,14,15,25,26,27,29,30,17,18,19,21,22, 2, 3, 4, 5, 7, 8, 9,10};
    #pragma unroll
    for (int k = 0; k < 22; ++k) {
        const float r  = pr[3*k + 0];
        const float th = pr[3*k + 1];
        const float ph = pr[3*k + 2];
        const float sp = __sinf(ph);
        const float cp = __cosf(ph);
        const float st = __sinf(th);
        const float ct = __cosf(th);
        const int c = chi[k], pa = par[k];
        const float rsp = r * sp;
        x[c][0] = fmaf(rsp, ct, x[pa][0]);   // r*sin(phi)*cos(theta)
        x[c][1] = fmaf(r,   cp, x[pa][1]);   // r*cos(phi)
        x[c][2] = fmaf(rsp, st, x[pa][2]);   // r*sin(phi)*sin(theta)
    }

    // ---- IDX_IGNORE <- IDX_EQUAL ----
    {
        constexpr int ig[6] = {16, 20, 23, 24, 28, 31};
        constexpr int eq[6] = {13, 19, 22, 13, 27, 30};
        #pragma unroll
        for (int i = 0; i < 6; ++i) {
            #pragma unroll
            for (int c = 0; c < 3; ++c) x[ig[i]][c] = x[eq[i]][c];
        }
    }

    // ---- store this lane's quarter: float4 #(4i+j), i=0..5 ----
    // Per instruction: 64 lanes cover rows g..g+15, each group of 4 lanes
    // writes one contiguous 64B chunk -> 16 full lines per store.
    float* o = out + (long)row * 96;
    #define XF(f) x[(f)/3][(f)%3]
    #pragma unroll
    for (int i = 0; i < 6; ++i) {
        const int f0 = (4*i + j) * 4;   // flat float index of this float4
        const float4 v = make_float4(XF(f0+0), XF(f0+1), XF(f0+2), XF(f0+3));
        *reinterpret_cast<float4*>(o + f0) = v;
    }
    #undef XF
}

extern "C" void kernel_launch(void* const* d_in, const int* in_sizes, int n_in,
                              void* d_out, int out_size, void* d_ws, size_t ws_size,
                              hipStream_t stream) {
    const float* obs  = (const float*)d_in[0];   // observed_pose (4096,16,96)
    const float* pred = (const float*)d_in[1];   // pred_pose     (4096,64,66)
    float* out = (float*)d_out;                  // (4096,64,96) fp32
    postproc_kernel<<<GRID, BLOCK, 0, stream>>>(obs, pred, out);
}

// Round 3
// 194.889 us; speedup vs baseline: 1.5325x; 1.5325x over previous
//
#include <hip/hip_runtime.h>

// Postprocess: spherical->xyz + kinematic-tree prefix sum.
// obs:  (4096, 16, 96) fp32   pred: (4096, 64, 66) fp32   out: (4096, 64, 96) fp32
//
// 4 lanes per row: lanes 4g+j (j=0..3) redundantly compute row g's full
// 22-edge chain (VALU ~free), each lane stores float4s #(4i+j), i=0..5.
// Per store instruction each 4-lane group writes one contiguous 64B chunk
// -> full-line stores, no read-for-ownership.
//
// Round-2 lesson: the lane's quarter must be selected with COMPILE-TIME
// indices. Runtime-indexed x[f(j)] put the whole array in scratch
// (WRITE_SIZE 492 MB = output + 390 MB of private-segment spill traffic).
// Here each output float is picked via 2-level cndmask on (j&1, j&2);
// every array subscript is a literal -> pure-register kernel.

constexpr int NB = 4096;
constexpr int NT = 64;
constexpr int ROWS = NB * NT;        // 262144 rows (b*64+t)
constexpr int BLOCK = 256;
constexpr int GRID = ROWS * 4 / BLOCK;

__global__ __launch_bounds__(BLOCK) void postproc_kernel(
    const float* __restrict__ obs,
    const float* __restrict__ pred,
    float* __restrict__ out)
{
    const int t   = blockIdx.x * BLOCK + threadIdx.x;
    const int row = t >> 2;          // global (b,t) row
    const int j   = t & 3;           // quarter index within the row
    const int b   = row >> 6;

    // ---- load 66 pred floats (r,theta,phi x22); 4-way shared lines in-wave ----
    float pr[66];
    {
        const float2* p2 = reinterpret_cast<const float2*>(pred + (long)row * 66);
        #pragma unroll
        for (int i = 0; i < 33; ++i) {
            const float2 v = p2[i];
            pr[2*i]   = v.x;
            pr[2*i+1] = v.y;
        }
    }

    float x[32][3];

    // ---- root joints from last observed frame (frame 15) ----
    {
        const float* ob = obs + (long)b * (16 * 96) + 15 * 96;
        constexpr int ic[4] = {0, 1, 6, 11};
        #pragma unroll
        for (int i = 0; i < 4; ++i) {
            #pragma unroll
            for (int c = 0; c < 3; ++c) x[ic[i]][c] = ob[ic[i]*3 + c];
        }
    }

    // ---- fused spherical->xyz + tree accumulation (topological order) ----
    constexpr int par[22] = {11,12,13,14,13,25,26,27,29,13,17,18,19,21, 1, 2, 3, 4, 6, 7, 8, 9};
    constexpr int chi[22] = {12,13,14,15,25,26,27,29,30,17,18,19,21,22, 2, 3, 4, 5, 7, 8, 9,10};
    #pragma unroll
    for (int k = 0; k < 22; ++k) {
        const float r  = pr[3*k + 0];
        const float th = pr[3*k + 1];
        const float ph = pr[3*k + 2];
        const float sp = __sinf(ph);
        const float cp = __cosf(ph);
        const float st = __sinf(th);
        const float ct = __cosf(th);
        const int c = chi[k], pa = par[k];
        const float rsp = r * sp;
        x[c][0] = fmaf(rsp, ct, x[pa][0]);   // r*sin(phi)*cos(theta)
        x[c][1] = fmaf(r,   cp, x[pa][1]);   // r*cos(phi)
        x[c][2] = fmaf(rsp, st, x[pa][2]);   // r*sin(phi)*sin(theta)
    }

    // ---- IDX_IGNORE <- IDX_EQUAL ----
    {
        constexpr int ig[6] = {16, 20, 23, 24, 28, 31};
        constexpr int eq[6] = {13, 19, 22, 13, 27, 30};
        #pragma unroll
        for (int i = 0; i < 6; ++i) {
            #pragma unroll
            for (int c = 0; c < 3; ++c) x[ig[i]][c] = x[eq[i]][c];
        }
    }

    // ---- select this lane's quarter with compile-time indices ----
    const bool jb0 = (j & 1) != 0;
    const bool jb1 = (j & 2) != 0;
    float q[24];                               // q[4i+c] = row float (4i+j)*4+c
    #define XF(f) x[(f)/3][(f)%3]
    #pragma unroll
    for (int i = 0; i < 6; ++i) {
        #pragma unroll
        for (int c = 0; c < 4; ++c) {
            const float v0 = XF((4*i + 0)*4 + c);
            const float v1 = XF((4*i + 1)*4 + c);
            const float v2 = XF((4*i + 2)*4 + c);
            const float v3 = XF((4*i + 3)*4 + c);
            const float lo = jb0 ? v1 : v0;
            const float hi = jb0 ? v3 : v2;
            q[4*i + c] = jb1 ? hi : lo;
        }
    }
    #undef XF

    // ---- store this lane's quarter: float4 #(4i+j), i=0..5 ----
    float* o = out + (long)row * 96;
    #pragma unroll
    for (int i = 0; i < 6; ++i) {
        const float4 v = make_float4(q[4*i+0], q[4*i+1], q[4*i+2], q[4*i+3]);
        *reinterpret_cast<float4*>(o + (4*i + j) * 4) = v;
    }
}

extern "C" void kernel_launch(void* const* d_in, const int* in_sizes, int n_in,
                              void* d_out, int out_size, void* d_ws, size_t ws_size,
                              hipStream_t stream) {
    const float* obs  = (const float*)d_in[0];   // observed_pose (4096,16,96)
    const float* pred = (const float*)d_in[1];   // pred_pose     (4096,64,66)
    float* out = (float*)d_out;                  // (4096,64,96) fp32
    postproc_kernel<<<GRID, BLOCK, 0, stream>>>(obs, pred, out);
}

// Round 4
// 176.523 us; speedup vs baseline: 1.6920x; 1.1040x over previous
//
#include <hip/hip_runtime.h>

// Postprocess: spherical->xyz + kinematic-tree prefix sum.
// obs:  (4096, 16, 96) fp32   pred: (4096, 64, 66) fp32   out: (4096, 64, 96) fp32
//
// Round-4 structure: LDS-staged on BOTH sides so every global access is a
// dense contiguous float4 stream.
//   A: block copies 64 pred rows (1056 float4, 16.9 KB) global->LDS, coalesced.
//   B: 4 lanes per row redundantly compute the row's 22-edge chain from LDS
//      (float2 reads, stride 66 dwords: banks 2g+2k -> conflict-free,
//       4-way same-address broadcast).
//   C: lane cndmask-selects its quarter (compile-time register indices only --
//      round-2 scratch lesson) and writes one float4 per group of 4 to
//      out_lds (row stride 25 float4 = 100 dwords -> structural-floor banks).
//   D: block streams 1536 float4 LDS->global, 1 KB per wave-instruction.
// Traffic floor ~171 MB => ~29 us at 6 TB/s.

constexpr int NB = 4096;
constexpr int NT = 64;
constexpr int ROWS = NB * NT;        // 262144 rows; tile = 64 rows = one batch
constexpr int BLOCK = 256;
constexpr int GRID = ROWS / 64;      // 4096 blocks

__global__ __launch_bounds__(BLOCK) void postproc_kernel(
    const float* __restrict__ obs,
    const float* __restrict__ pred,
    float* __restrict__ out)
{
    __shared__ float4 pred_lds[64 * 66 / 4];   // 1056 float4 = 16.9 KB (16896 B tile)
    __shared__ float4 out_lds[64 * 25];        // 64 rows x 25 float4 (stride 100 dwords)

    const int tid = threadIdx.x;
    const int blk = blockIdx.x;                // == batch b; rows [blk*64, blk*64+64)
    const int g   = tid >> 2;                  // local row 0..63
    const int j   = tid & 3;                   // quarter index

    // ---- Stage A: coalesced global->LDS copy of the pred tile ----
    {
        const float4* gp = reinterpret_cast<const float4*>(pred + (size_t)blk * (64 * 66));
        #pragma unroll
        for (int it = 0; it < 5; ++it) {
            const int idx = it * BLOCK + tid;
            if (idx < 1056) pred_lds[idx] = gp[idx];
        }
    }
    __syncthreads();

    // ---- Stage B: read this row's 66 floats from LDS (conflict-free) ----
    float pr[66];
    {
        const float2* pl = reinterpret_cast<const float2*>(pred_lds) + g * 33;
        #pragma unroll
        for (int k = 0; k < 33; ++k) {
            const float2 v = pl[k];
            pr[2*k]   = v.x;
            pr[2*k+1] = v.y;
        }
    }

    float x[32][3];

    // ---- root joints from last observed frame (frame 15); b == blk ----
    {
        const float* ob = obs + (size_t)blk * (16 * 96) + 15 * 96;
        constexpr int ic[4] = {0, 1, 6, 11};
        #pragma unroll
        for (int i = 0; i < 4; ++i) {
            #pragma unroll
            for (int c = 0; c < 3; ++c) x[ic[i]][c] = ob[ic[i]*3 + c];
        }
    }

    // ---- fused spherical->xyz + tree accumulation (topological order) ----
    constexpr int par[22] = {11,12,13,14,13,25,26,27,29,13,17,18,19,21, 1, 2, 3, 4, 6, 7, 8, 9};
    constexpr int chi[22] = {12,13,14,15,25,26,27,29,30,17,18,19,21,22, 2, 3, 4, 5, 7, 8, 9,10};
    #pragma unroll
    for (int k = 0; k < 22; ++k) {
        const float r  = pr[3*k + 0];
        const float th = pr[3*k + 1];
        const float ph = pr[3*k + 2];
        const float sp = __sinf(ph);
        const float cp = __cosf(ph);
        const float st = __sinf(th);
        const float ct = __cosf(th);
        const int c = chi[k], pa = par[k];
        const float rsp = r * sp;
        x[c][0] = fmaf(rsp, ct, x[pa][0]);   // r*sin(phi)*cos(theta)
        x[c][1] = fmaf(r,   cp, x[pa][1]);   // r*cos(phi)
        x[c][2] = fmaf(rsp, st, x[pa][2]);   // r*sin(phi)*sin(theta)
    }

    // ---- IDX_IGNORE <- IDX_EQUAL ----
    {
        constexpr int ig[6] = {16, 20, 23, 24, 28, 31};
        constexpr int eq[6] = {13, 19, 22, 13, 27, 30};
        #pragma unroll
        for (int i = 0; i < 6; ++i) {
            #pragma unroll
            for (int c = 0; c < 3; ++c) x[ig[i]][c] = x[eq[i]][c];
        }
    }

    // ---- Stage C: select this lane's quarter (compile-time indices) and
    //      write one float4 per i to out_lds (runtime j only in the ADDRESS) ----
    {
        const bool jb0 = (j & 1) != 0;
        const bool jb1 = (j & 2) != 0;
        #define XF(f) x[(f)/3][(f)%3]
        #pragma unroll
        for (int i = 0; i < 6; ++i) {
            float q[4];
            #pragma unroll
            for (int c = 0; c < 4; ++c) {
                const float v0 = XF((4*i + 0)*4 + c);
                const float v1 = XF((4*i + 1)*4 + c);
                const float v2 = XF((4*i + 2)*4 + c);
                const float v3 = XF((4*i + 3)*4 + c);
                const float lo = jb0 ? v1 : v0;
                const float hi = jb0 ? v3 : v2;
                q[c] = jb1 ? hi : lo;
            }
            out_lds[g * 25 + (4*i + j)] = make_float4(q[0], q[1], q[2], q[3]);
        }
        #undef XF
    }
    __syncthreads();

    // ---- Stage D: stream LDS -> global, fully coalesced float4 ----
    {
        float4* og = reinterpret_cast<float4*>(out) + (size_t)blk * 1536;
        #pragma unroll
        for (int it = 0; it < 6; ++it) {
            const int fi  = it * BLOCK + tid;      // 0..1535
            const int row = fi / 24;               // magic-mul div
            const int q4  = fi - row * 24;
            og[fi] = out_lds[row * 25 + q4];
        }
    }
}

extern "C" void kernel_launch(void* const* d_in, const int* in_sizes, int n_in,
                              void* d_out, int out_size, void* d_ws, size_t ws_size,
                              hipStream_t stream) {
    const float* obs  = (const float*)d_in[0];   // observed_pose (4096,16,96)
    const float* pred = (const float*)d_in[1];   // pred_pose     (4096,64,66)
    float* out = (float*)d_out;                  // (4096,64,96) fp32
    postproc_kernel<<<GRID, BLOCK, 0, stream>>>(obs, pred, out);
}

// Round 5
// 169.224 us; speedup vs baseline: 1.7650x; 1.0431x over previous
//
#include <hip/hip_runtime.h>

// Postprocess: spherical->xyz + kinematic-tree prefix sum.
// obs:  (4096, 16, 96) fp32   pred: (4096, 64, 66) fp32   out: (4096, 64, 96) fp32
//
// Round-5: single UNION LDS buffer (25.6 KB) reused for pred staging and
// out staging -> 6 blocks/CU (24 waves) vs round-4's 3 blocks (42.5 KB).
// Phase-serialized blocks starve HBM at low occupancy; doubling resident
// blocks doubles the number of independent load/compute/store pipelines.
//   A: block copies 64 pred rows (1056 float4) global->LDS, coalesced.
//   B: 4 lanes/row read the row from LDS (float2, stride 66 dw: conflict-free)
//      and redundantly compute the 22-edge chain (compiler interleaves
//      ds_reads into the trans-heavy chain; keeps VGPR low like round 3's 52).
//   sync (union-buffer reuse barrier)
//   C: lane cndmask-selects its quarter (ALL register indices compile-time --
//      round-2 scratch lesson) -> one float4 per lane-group to lds[g*25+4i+j].
//   D: block streams 1536 float4 LDS->global, fully coalesced.
// Traffic floor ~172 MB => ~27 us at 6.5 TB/s.

constexpr int NB = 4096;
constexpr int NT = 64;
constexpr int ROWS = NB * NT;        // 262144 rows; tile = 64 rows = one batch
constexpr int BLOCK = 256;
constexpr int GRID = ROWS / 64;      // 4096 blocks

__global__ __launch_bounds__(BLOCK, 6) void postproc_kernel(
    const float* __restrict__ obs,
    const float* __restrict__ pred,
    float* __restrict__ out)
{
    __shared__ float4 lds[1600];               // 25.6 KB union: pred tile / out tile

    const int tid = threadIdx.x;
    const int blk = blockIdx.x;                // == batch b; rows [blk*64, blk*64+64)
    const int g   = tid >> 2;                  // local row 0..63
    const int j   = tid & 3;                   // quarter index

    // ---- root joints from last observed frame (frame 15); uniform address
    //      across the block -> scalar loads, issued early ----
    float rootv[4][3];
    {
        const float* ob = obs + (size_t)blk * (16 * 96) + 15 * 96;
        constexpr int ic[4] = {0, 1, 6, 11};
        #pragma unroll
        for (int i = 0; i < 4; ++i) {
            #pragma unroll
            for (int c = 0; c < 3; ++c) rootv[i][c] = ob[ic[i]*3 + c];
        }
    }

    // ---- Stage A: coalesced global->LDS copy of the pred tile ----
    {
        const float4* gp = reinterpret_cast<const float4*>(pred + (size_t)blk * (64 * 66));
        #pragma unroll
        for (int it = 0; it < 5; ++it) {
            const int idx = it * BLOCK + tid;
            if (idx < 1056) lds[idx] = gp[idx];
        }
    }
    __syncthreads();

    // ---- Stage B: row from LDS (conflict-free) + fused chain compute ----
    float pr[66];
    {
        const float2* pl = reinterpret_cast<const float2*>(lds) + g * 33;
        #pragma unroll
        for (int k = 0; k < 33; ++k) {
            const float2 v = pl[k];
            pr[2*k]   = v.x;
            pr[2*k+1] = v.y;
        }
    }

    float x[32][3];
    {
        constexpr int ic[4] = {0, 1, 6, 11};
        #pragma unroll
        for (int i = 0; i < 4; ++i) {
            #pragma unroll
            for (int c = 0; c < 3; ++c) x[ic[i]][c] = rootv[i][c];
        }
    }

    // topological order: parents final before children
    constexpr int par[22] = {11,12,13,14,13,25,26,27,29,13,17,18,19,21, 1, 2, 3, 4, 6, 7, 8, 9};
    constexpr int chi[22] = {12,13,14,15,25,26,27,29,30,17,18,19,21,22, 2, 3, 4, 5, 7, 8, 9,10};
    #pragma unroll
    for (int k = 0; k < 22; ++k) {
        const float r  = pr[3*k + 0];
        const float th = pr[3*k + 1];
        const float ph = pr[3*k + 2];
        const float sp = __sinf(ph);
        const float cp = __cosf(ph);
        const float st = __sinf(th);
        const float ct = __cosf(th);
        const int c = chi[k], pa = par[k];
        const float rsp = r * sp;
        x[c][0] = fmaf(rsp, ct, x[pa][0]);   // r*sin(phi)*cos(theta)
        x[c][1] = fmaf(r,   cp, x[pa][1]);   // r*cos(phi)
        x[c][2] = fmaf(rsp, st, x[pa][2]);   // r*sin(phi)*sin(theta)
    }

    // IDX_IGNORE <- IDX_EQUAL
    {
        constexpr int ig[6] = {16, 20, 23, 24, 28, 31};
        constexpr int eq[6] = {13, 19, 22, 13, 27, 30};
        #pragma unroll
        for (int i = 0; i < 6; ++i) {
            #pragma unroll
            for (int c = 0; c < 3; ++c) x[ig[i]][c] = x[eq[i]][c];
        }
    }

    __syncthreads();   // all B-reads done -> safe to overwrite union buffer

    // ---- Stage C: quarter select (compile-time indices) -> LDS ----
    {
        const bool jb0 = (j & 1) != 0;
        const bool jb1 = (j & 2) != 0;
        #define XF(f) x[(f)/3][(f)%3]
        #pragma unroll
        for (int i = 0; i < 6; ++i) {
            float q[4];
            #pragma unroll
            for (int c = 0; c < 4; ++c) {
                const float v0 = XF((4*i + 0)*4 + c);
                const float v1 = XF((4*i + 1)*4 + c);
                const float v2 = XF((4*i + 2)*4 + c);
                const float v3 = XF((4*i + 3)*4 + c);
                const float lo = jb0 ? v1 : v0;
                const float hi = jb0 ? v3 : v2;
                q[c] = jb1 ? hi : lo;
            }
            lds[g * 25 + (4*i + j)] = make_float4(q[0], q[1], q[2], q[3]);
        }
        #undef XF
    }
    __syncthreads();

    // ---- Stage D: stream LDS -> global, fully coalesced float4 ----
    {
        float4* og = reinterpret_cast<float4*>(out) + (size_t)blk * 1536;
        #pragma unroll
        for (int it = 0; it < 6; ++it) {
            const int fi  = it * BLOCK + tid;      // 0..1535
            const int row = fi / 24;               // magic-mul div
            const int q4  = fi - row * 24;
            og[fi] = lds[row * 25 + q4];
        }
    }
}

extern "C" void kernel_launch(void* const* d_in, const int* in_sizes, int n_in,
                              void* d_out, int out_size, void* d_ws, size_t ws_size,
                              hipStream_t stream) {
    const float* obs  = (const float*)d_in[0];   // observed_pose (4096,16,96)
    const float* pred = (const float*)d_in[1];   // pred_pose     (4096,64,66)
    float* out = (float*)d_out;                  // (4096,64,96) fp32
    postproc_kernel<<<GRID, BLOCK, 0, stream>>>(obs, pred, out);
}